// Round 7
// baseline (379.583 us; speedup 1.0000x reference)
//
#include <hip/hip_runtime.h>
#include <hip/hip_bf16.h>

#define NT 65536   // text rows (M)
#define NL 1024    // label rows (N)
#define DD 256     // feature dim (K)

#define BM 128
#define BN 128
#define BK 64

typedef __attribute__((ext_vector_type(4))) float f32x4;
typedef __attribute__((ext_vector_type(8))) short bf16x8;

__device__ inline short f2bf(float x) {
    union { __hip_bfloat16 b; short s; } u;
    u.b = __float2bfloat16(x);   // RNE
    return u.s;
}

// Fully-fused cosine similarity:
//   C[m][l] = dot_bf16(A[m], B[l]) / (||A[m]|| * ||B[l]||)   (fp32 norms)
// One kernel. 128x128 tile, BK=64, 512 thr (8 waves, 2Mx4N of 64x32).
// Staging: reg-load fp32 (8 floats/thread/matrix/row-pair), cvt->bf16x8,
// ds_write_b128 to XOR-swizzled slot (chunk^(row&7)) -> bank-uniform writes
// and conflict-free MFMA reads. Row sumsq accumulated in-register during
// conversion (fp32-exact norms), 8-lane shfl_xor reduce -> LDS.
__global__ __launch_bounds__(512, 4) void cosim_k(const float* __restrict__ A,
                                                  const float* __restrict__ Bm,
                                                  float* __restrict__ C) {
    __shared__ short As[BM * BK];   // 16 KB
    __shared__ short Bs[BN * BK];   // 16 KB
    __shared__ float rnA[BM];
    __shared__ float rnB[BN];

    const int tid  = threadIdx.x;
    const int lane = tid & 63;
    const int w    = tid >> 6;       // 0..7
    const int wr   = w >> 2;         // wave row 0..1 (64 rows)
    const int wc   = w & 3;          // wave col 0..3 (32 cols)

    // XCD-aware swizzle: each XCD owns a contiguous M range; the 8 column
    // tiles of one M-range run on the same XCD -> A panel stays in its L2.
    const int orig = blockIdx.x;
    const int id   = (orig & 7) * (4096 / 8) + (orig >> 3);
    const int bx   = id & 7;
    const int by   = id >> 3;
    const int m0   = by * BM;
    const int l0   = bx * BN;

    // staging assignment: thread -> rows {sr, sr+64}, 16B chunk sch (8 bf16)
    const int sr  = tid >> 3;        // 0..63
    const int sch = tid & 7;         // chunk 0..7 within 64-col row slice
    const int scs = sch ^ (sr & 7);  // swizzled LDS chunk slot ((sr+64)&7 == sr&7)

    const float* Ap0 = A  + (size_t)(m0 + sr)      * DD + sch * 8;
    const float* Ap1 = A  + (size_t)(m0 + sr + 64) * DD + sch * 8;
    const float* Bp0 = Bm + (size_t)(l0 + sr)      * DD + sch * 8;
    const float* Bp1 = Bm + (size_t)(l0 + sr + 64) * DD + sch * 8;

    f32x4 a00, a01, a10, a11, b00, b01, b10, b11;
    float sa0 = 0.f, sa1 = 0.f, sb0 = 0.f, sb1 = 0.f;

    auto ldregs = [&](int kt) {
        const f32x4* pa0 = reinterpret_cast<const f32x4*>(Ap0 + kt * BK);
        const f32x4* pa1 = reinterpret_cast<const f32x4*>(Ap1 + kt * BK);
        const f32x4* pb0 = reinterpret_cast<const f32x4*>(Bp0 + kt * BK);
        const f32x4* pb1 = reinterpret_cast<const f32x4*>(Bp1 + kt * BK);
        a00 = pa0[0]; a01 = pa0[1];
        a10 = pa1[0]; a11 = pa1[1];
        b00 = pb0[0]; b01 = pb0[1];
        b10 = pb1[0]; b11 = pb1[1];
    };
    auto sq8 = [](f32x4 lo, f32x4 hi) {
        return lo[0]*lo[0] + lo[1]*lo[1] + lo[2]*lo[2] + lo[3]*lo[3]
             + hi[0]*hi[0] + hi[1]*hi[1] + hi[2]*hi[2] + hi[3]*hi[3];
    };
    auto cvt8 = [](f32x4 lo, f32x4 hi) {
        bf16x8 r;
        r[0] = f2bf(lo[0]); r[1] = f2bf(lo[1]); r[2] = f2bf(lo[2]); r[3] = f2bf(lo[3]);
        r[4] = f2bf(hi[0]); r[5] = f2bf(hi[1]); r[6] = f2bf(hi[2]); r[7] = f2bf(hi[3]);
        return r;
    };

    const int fr = lane & 15;
    const int fq = lane >> 4;
    f32x4 acc[4][2] = {};

    ldregs(0);
#pragma unroll
    for (int kt = 0; kt < DD / BK; ++kt) {
        // convert + accumulate norms + stash to swizzled LDS
        sa0 += sq8(a00, a01);  sa1 += sq8(a10, a11);
        sb0 += sq8(b00, b01);  sb1 += sq8(b10, b11);
        *reinterpret_cast<bf16x8*>(&As[sr        * BK + scs * 8]) = cvt8(a00, a01);
        *reinterpret_cast<bf16x8*>(&As[(sr + 64) * BK + scs * 8]) = cvt8(a10, a11);
        *reinterpret_cast<bf16x8*>(&Bs[sr        * BK + scs * 8]) = cvt8(b00, b01);
        *reinterpret_cast<bf16x8*>(&Bs[(sr + 64) * BK + scs * 8]) = cvt8(b10, b11);
        if (kt < DD / BK - 1) ldregs(kt + 1);   // fly under MFMA phase
        __syncthreads();                         // stash visible

#pragma unroll
        for (int ks = 0; ks < 2; ++ks) {
            bf16x8 af[4], bfr[2];
#pragma unroll
            for (int i = 0; i < 4; ++i) {
                int row = wr * 64 + i * 16 + fr;
                int ck  = (ks * 4 + fq) ^ (row & 7);   // deswizzle
                af[i] = *reinterpret_cast<const bf16x8*>(&As[row * BK + ck * 8]);
            }
#pragma unroll
            for (int j = 0; j < 2; ++j) {
                int row = wc * 32 + j * 16 + fr;
                int ck  = (ks * 4 + fq) ^ (row & 7);
                bfr[j] = *reinterpret_cast<const bf16x8*>(&Bs[row * BK + ck * 8]);
            }
#pragma unroll
            for (int i = 0; i < 4; ++i)
#pragma unroll
                for (int j = 0; j < 2; ++j)
                    acc[i][j] = __builtin_amdgcn_mfma_f32_16x16x32_bf16(
                        af[i], bfr[j], acc[i][j], 0, 0, 0);
        }
        __syncthreads();                         // reads done; LDS reusable
    }

    // reduce row sumsq across the 8 chunk-threads (adjacent lanes, bits 0..2)
#pragma unroll
    for (int off = 1; off < 8; off <<= 1) {
        sa0 += __shfl_xor(sa0, off);
        sa1 += __shfl_xor(sa1, off);
        sb0 += __shfl_xor(sb0, off);
        sb1 += __shfl_xor(sb1, off);
    }
    if (sch == 0) {
        rnA[sr]      = 1.0f / fmaxf(sqrtf(sa0), 1e-20f);
        rnA[sr + 64] = 1.0f / fmaxf(sqrtf(sa1), 1e-20f);
        rnB[sr]      = 1.0f / fmaxf(sqrtf(sb0), 1e-20f);
        rnB[sr + 64] = 1.0f / fmaxf(sqrtf(sb1), 1e-20f);
    }
    __syncthreads();

    // epilogue: C/D layout col=lane&15, row=(lane>>4)*4+reg
    const int rq = lane >> 4;
    const int cc = lane & 15;
#pragma unroll
    for (int i = 0; i < 4; ++i) {
#pragma unroll
        for (int rr = 0; rr < 4; ++rr) {
            int lr = wr * 64 + i * 16 + rq * 4 + rr;   // local row
            float rsc = rnA[lr];
            float* crow = C + (size_t)(m0 + lr) * NL + l0;
#pragma unroll
            for (int j = 0; j < 2; ++j) {
                int lc = wc * 32 + j * 16 + cc;        // local col
                crow[lc] = acc[i][j][rr] * rsc * rnB[lc];
            }
        }
    }
}

extern "C" void kernel_launch(void* const* d_in, const int* in_sizes, int n_in,
                              void* d_out, int out_size, void* d_ws, size_t ws_size,
                              hipStream_t stream) {
    const float* A  = (const float*)d_in[0];   // [65536,256] fp32
    const float* Bm = (const float*)d_in[1];   // [1024,256]  fp32
    float* C = (float*)d_out;                  // [65536,1024] fp32
    (void)d_ws; (void)ws_size;

    cosim_k<<<(NL / BN) * (NT / BM), 512, 0, stream>>>(A, Bm, C);
}

// Round 8
// 342.997 us; speedup vs baseline: 1.1067x; 1.1067x over previous
//
#include <hip/hip_runtime.h>
#include <hip/hip_bf16.h>

#define NT 65536   // text rows (M)
#define NL 1024    // label rows (N)
#define DD 256     // feature dim (K)

#define BM 128
#define BN 128
#define BK 64
#define TPB 16     // M-tiles per block (persistent strip)

typedef __attribute__((ext_vector_type(4))) float f32x4;
typedef __attribute__((ext_vector_type(8))) short bf16x8;

__device__ inline short f2bf(float x) {
    union { __hip_bfloat16 b; short s; } u;
    u.b = __float2bfloat16(x);   // RNE
    return u.s;
}

__device__ inline void gload_lds16(const void* g, void* l) {
    __builtin_amdgcn_global_load_lds((const __attribute__((address_space(1))) void*)g,
                                     (__attribute__((address_space(3))) void*)l,
                                     16, 0, 0);
}

// ---------------- prep: bf16 conversion + reciprocal norms ----------------
__global__ __launch_bounds__(256) void prep_k(const float* __restrict__ A,
                                              const float* __restrict__ Bm,
                                              short* __restrict__ Abf,
                                              short* __restrict__ Bbf,
                                              float* __restrict__ rt,
                                              float* __restrict__ rl) {
    int gw   = (blockIdx.x * 256 + threadIdx.x) >> 6;
    int lane = threadIdx.x & 63;
    if (gw >= NT + NL) return;
    const float* src = (gw < NT) ? (A + (size_t)gw * DD) : (Bm + (size_t)(gw - NT) * DD);
    short*       dst = (gw < NT) ? (Abf + (size_t)gw * DD) : (Bbf + (size_t)(gw - NT) * DD);
    float4 v = reinterpret_cast<const float4*>(src)[lane];
    short4 o;
    o.x = f2bf(v.x); o.y = f2bf(v.y); o.z = f2bf(v.z); o.w = f2bf(v.w);
    reinterpret_cast<short4*>(dst)[lane] = o;
    float s = v.x * v.x + v.y * v.y + v.z * v.z + v.w * v.w;
#pragma unroll
    for (int off = 32; off > 0; off >>= 1) s += __shfl_xor(s, off);
    if (lane == 0) {
        float r = 1.0f / fmaxf(sqrtf(s), 1e-20f);
        if (gw < NT) rt[gw] = r; else rl[gw - NT] = r;
    }
}

// ---------------- persistent-strip bf16 GEMM, counted-vmcnt pipeline ------
// 256 blocks (1/CU, 512 thr, 8 waves 2Mx4N). Block = one 2048-row M strip x
// one 128-col N tile. B-tile (full K) staged once; A staged as 64 BK=64
// stages into a 4-deep LDS ring, prefetch 2 ahead, counted s_waitcnt vmcnt
// + raw s_barrier (one per stage, never vmcnt(0) mid-loop). Epilogue stores
// ride the VMEM queue; kt0/kt1 waits (36/34) skip over them (in-order
// retirement, m135). Norms preloaded to LDS -> no other VMEM in the loop.
__global__ __launch_bounds__(512, 2) void cosim_bf_k(const short* __restrict__ Abf,
                                                     const short* __restrict__ Bbf,
                                                     const float* __restrict__ rt,
                                                     const float* __restrict__ rl,
                                                     float* __restrict__ C) {
    __shared__ short Bs[BN * DD];        // 64 KB, full-K B tile
    __shared__ short As[4][BM * BK];     // 64 KB, 4-deep A ring
    __shared__ float rnA[TPB * BM];      // 8 KB
    __shared__ float rnB[BN];            // 0.5 KB

    const int tid  = threadIdx.x;
    const int lane = tid & 63;
    const int w    = tid >> 6;       // 0..7
    const int wr   = w >> 2;         // wave row 0..1 (64 rows)
    const int wc   = w & 3;          // wave col 0..3 (32 cols)

    // XCD k (= bid&7 under round-robin dispatch) owns rows [k*8192,(k+1)*8192):
    // A panel read from HBM once, reused across its 8 bx blocks via L2.
    const int xcd   = blockIdx.x & 7;
    const int g2    = blockIdx.x >> 3;   // 0..31
    const int bx    = g2 & 7;
    const int sub   = g2 >> 3;           // 0..3
    const int strip = xcd * 4 + sub;     // 0..31
    const int m0b   = strip * (TPB * BM);
    const int l0    = bx * BN;

    // ---- stage B (full K), source-chunk XOR swizzle ----
    {
        const int r2 = lane >> 5;        // row within pair
        const int ch = lane & 31;        // 16B chunk 0..31
#pragma unroll
        for (int i = 0; i < 8; ++i) {
            int rbase = w * 16 + i * 2;
            int row   = rbase + r2;
            int cg    = ch ^ (row & 7);
            gload_lds16(Bbf + (size_t)(l0 + row) * DD + cg * 8, &Bs[rbase * DD]);
        }
    }
    // ---- preload reciprocal norms into LDS ----
#pragma unroll
    for (int i = 0; i < 4; ++i) {
        int r = tid + i * 512;
        rnA[r] = rt[m0b + r];
    }
    if (tid < BN) rnB[tid] = rl[l0 + tid];
    __syncthreads();                     // drains B-stage vmcnt + norm lgkm

    // ---- A staging: stage g = tile (g>>2), k-slice (g&3), ring buf g&3 ----
    const int r8  = lane >> 3;
    const int ch8 = lane & 7;
    const int cg8 = ch8 ^ r8;            // r8 == row&7 for our row decomposition
    auto stageA = [&](int g) {
        const short* base = Abf + (size_t)(m0b + (g >> 2) * BM) * DD + (g & 3) * BK;
        short* dst = As[g & 3];
#pragma unroll
        for (int i = 0; i < 2; ++i) {
            int rbase = w * 16 + i * 8;
            gload_lds16(base + (size_t)(rbase + r8) * DD + cg8 * 8, &dst[rbase * BK]);
        }
    };

    stageA(0);
    stageA(1);

    const int fr = lane & 15;
    const int fq = lane >> 4;
    const int cc = lane & 15;

#pragma unroll 1
    for (int t = 0; t < TPB; ++t) {
        f32x4 acc[4][2] = {};
#pragma unroll
        for (int kt = 0; kt < 4; ++kt) {
            const int g = t * 4 + kt;
            // queue (oldest->newest) at tile boundary: [s_g, s_g+1, stores(32/thr? 32 insts), s_g+2]
            if (kt == 0) {
                stageA(g + 2);
                if (t == 0) asm volatile("s_waitcnt vmcnt(4)" ::: "memory");
                else        asm volatile("s_waitcnt vmcnt(36)" ::: "memory");
            } else if (kt == 1) {
                stageA(g + 2);
                if (t == 0) asm volatile("s_waitcnt vmcnt(4)" ::: "memory");
                else        asm volatile("s_waitcnt vmcnt(34)" ::: "memory");
            } else if (kt == 2) {
                if (t < TPB - 1) { stageA(g + 2); asm volatile("s_waitcnt vmcnt(4)" ::: "memory"); }
                else             { asm volatile("s_waitcnt vmcnt(2)" ::: "memory"); }
            } else {
                if (t < TPB - 1) { stageA(g + 2); asm volatile("s_waitcnt vmcnt(4)" ::: "memory"); }
                else             { asm volatile("s_waitcnt vmcnt(0)" ::: "memory"); }
            }
            __builtin_amdgcn_s_barrier();   // all waves' stage(g) landed

            const short* A_ = As[g & 3];
#pragma unroll
            for (int ks = 0; ks < 2; ++ks) {
                bf16x8 af[4], bf2[2];
#pragma unroll
                for (int i = 0; i < 4; ++i) {
                    int row = wr * 64 + i * 16 + fr;
                    int ck  = (ks * 4 + fq) ^ (row & 7);        // deswizzle
                    af[i] = *reinterpret_cast<const bf16x8*>(&A_[row * BK + ck * 8]);
                }
#pragma unroll
                for (int j = 0; j < 2; ++j) {
                    int row = wc * 32 + j * 16 + fr;
                    int c   = kt * 8 + ks * 4 + fq;              // full-K chunk
                    int ck  = c ^ (row & 7);
                    bf2[j] = *reinterpret_cast<const bf16x8*>(&Bs[row * DD + ck * 8]);
                }
#pragma unroll
                for (int i = 0; i < 4; ++i)
#pragma unroll
                    for (int j = 0; j < 2; ++j)
                        acc[i][j] = __builtin_amdgcn_mfma_f32_16x16x32_bf16(
                            af[i], bf2[j], acc[i][j], 0, 0, 0);
            }
            // no trailing barrier: 4-deep ring + barrier-per-iter bounds skew
            // to 1 iter; writes (g+2)&3 never collide with reads g&3/(g-1)&3.
        }

        // epilogue tile t (LDS norms only; stores ride the VMEM queue)
        const int m0 = m0b + t * BM;
#pragma unroll
        for (int i = 0; i < 4; ++i) {
#pragma unroll
            for (int rr = 0; rr < 4; ++rr) {
                int lr = wr * 64 + i * 16 + fq * 4 + rr;
                float rs = rnA[t * BM + lr];
                float* crow = C + (size_t)(m0 + lr) * NL + l0;
#pragma unroll
                for (int j = 0; j < 2; ++j) {
                    int lc = wc * 32 + j * 16 + cc;
                    crow[lc] = acc[i][j][rr] * rs * rnB[lc];
                }
            }
        }
    }
}

// ---------------- fallback (round-1 fused path, ws too small) -------------
__global__ __launch_bounds__(256) void norms_k(const float* __restrict__ A,
                                               const float* __restrict__ Bm,
                                               float* __restrict__ rt,
                                               float* __restrict__ rl) {
    int gw   = (blockIdx.x * 256 + threadIdx.x) >> 6;
    int lane = threadIdx.x & 63;
    if (gw >= NT + NL) return;
    const float* src = (gw < NT) ? (A + (size_t)gw * DD) : (Bm + (size_t)(gw - NT) * DD);
    float4 v = reinterpret_cast<const float4*>(src)[lane];
    float s = v.x * v.x + v.y * v.y + v.z * v.z + v.w * v.w;
#pragma unroll
    for (int off = 32; off > 0; off >>= 1) s += __shfl_xor(s, off);
    if (lane == 0) {
        float r = 1.0f / fmaxf(sqrtf(s), 1e-20f);
        if (gw < NT) rt[gw] = r; else rl[gw - NT] = r;
    }
}

__global__ __launch_bounds__(256, 2) void cosim_fused_k(const float* __restrict__ A,
                                                        const float* __restrict__ Bm,
                                                        const float* __restrict__ rt,
                                                        const float* __restrict__ rl,
                                                        float* __restrict__ C) {
    __shared__ short As[BM * BK];
    __shared__ short Bs[BN * BK];
    const int tid  = threadIdx.x;
    const int lane = tid & 63;
    const int wid  = tid >> 6;
    const int wr   = wid >> 1;
    const int wc   = wid & 1;
    const int orig = blockIdx.x;
    const int id   = (orig & 7) * (4096 / 8) + (orig >> 3);
    const int bx   = id & 7;
    const int by   = id >> 3;
    const int m0 = by * BM;
    const int l0 = bx * BN;
    const int srow = tid >> 4;
    const int sc4  = tid & 15;
    f32x4 ra[8], rb[8];
    auto loadg = [&](int kt) {
        const float* pa = A  + (size_t)m0 * DD + kt * BK;
        const float* pb = Bm + (size_t)l0 * DD + kt * BK;
#pragma unroll
        for (int i = 0; i < 8; ++i) {
            int row = srow + i * 16;
            ra[i] = reinterpret_cast<const f32x4*>(pa + (size_t)row * DD)[sc4];
            rb[i] = reinterpret_cast<const f32x4*>(pb + (size_t)row * DD)[sc4];
        }
    };
    auto stash = [&]() {
#pragma unroll
        for (int i = 0; i < 8; ++i) {
            int row = srow + i * 16;
            short4 pa, pb;
            pa.x = f2bf(ra[i].x); pa.y = f2bf(ra[i].y);
            pa.z = f2bf(ra[i].z); pa.w = f2bf(ra[i].w);
            pb.x = f2bf(rb[i].x); pb.y = f2bf(rb[i].y);
            pb.z = f2bf(rb[i].z); pb.w = f2bf(rb[i].w);
            *reinterpret_cast<short4*>(&As[row * BK + sc4 * 4]) = pa;
            *reinterpret_cast<short4*>(&Bs[row * BK + sc4 * 4]) = pb;
        }
    };
    f32x4 acc[4][4] = {};
    loadg(0);
#pragma unroll
    for (int kt = 0; kt < DD / BK; ++kt) {
        __syncthreads();
        stash();
        __syncthreads();
        if (kt < DD / BK - 1) loadg(kt + 1);
#pragma unroll
        for (int ks = 0; ks < 2; ++ks) {
            bf16x8 af[4], bfr[4];
            const int kof = ks * 32 + (lane >> 4) * 8;
            const int ar  = wr * 64 + (lane & 15);
            const int bc  = wc * 64 + (lane & 15);
#pragma unroll
            for (int i = 0; i < 4; ++i)
                af[i] = *reinterpret_cast<const bf16x8*>(&As[(ar + i * 16) * BK + kof]);
#pragma unroll
            for (int j = 0; j < 4; ++j)
                bfr[j] = *reinterpret_cast<const bf16x8*>(&Bs[(bc + j * 16) * BK + kof]);
#pragma unroll
            for (int i = 0; i < 4; ++i)
#pragma unroll
                for (int j = 0; j < 4; ++j)
                    acc[i][j] = __builtin_amdgcn_mfma_f32_16x16x32_bf16(
                        af[i], bfr[j], acc[i][j], 0, 0, 0);
        }
    }
    const int crow0 = m0 + wr * 64;
    const int ccol0 = l0 + wc * 64;
    const int rq = lane >> 4;
    const int cc = lane & 15;
#pragma unroll
    for (int i = 0; i < 4; ++i) {
#pragma unroll
        for (int r = 0; r < 4; ++r) {
            int row = crow0 + i * 16 + rq * 4 + r;
            float rsc = rt[row];
            float* crow = C + (size_t)row * NL;
#pragma unroll
            for (int j = 0; j < 4; ++j) {
                int col = ccol0 + j * 16 + cc;
                crow[col] = acc[i][j][r] * rsc * rl[col];
            }
        }
    }
}

extern "C" void kernel_launch(void* const* d_in, const int* in_sizes, int n_in,
                              void* d_out, int out_size, void* d_ws, size_t ws_size,
                              hipStream_t stream) {
    const float* A  = (const float*)d_in[0];   // [65536,256] fp32
    const float* Bm = (const float*)d_in[1];   // [1024,256]  fp32
    float* C = (float*)d_out;                  // [65536,1024] fp32

    const size_t abf_elems = (size_t)NT * DD;
    const size_t bbf_elems = (size_t)NL * DD;
    const size_t need = (abf_elems + bbf_elems) * sizeof(short)
                      + (NT + NL) * sizeof(float);

    if (ws_size >= need) {
        short* Abf = (short*)d_ws;
        short* Bbf = Abf + abf_elems;
        float* rt  = (float*)(Bbf + bbf_elems);
        float* rl  = rt + NT;
        prep_k<<<(NT + NL) / 4, 256, 0, stream>>>(A, Bm, Abf, Bbf, rt, rl);
        cosim_bf_k<<<256, 512, 0, stream>>>(Abf, Bbf, rt, rl, C);
    } else {
        float* rt = (float*)d_ws;
        float* rl = rt + NT;
        norms_k<<<(NT + NL) / 4, 256, 0, stream>>>(A, Bm, rt, rl);
        cosim_fused_k<<<(NL / BN) * (NT / BM), 256, 0, stream>>>(A, Bm, rt, rl, C);
    }
}

// Round 9
// 316.129 us; speedup vs baseline: 1.2007x; 1.0850x over previous
//
#include <hip/hip_runtime.h>
#include <hip/hip_bf16.h>

#define NT 65536   // text rows (M)
#define NL 1024    // label rows (N)
#define DD 256     // feature dim (K)

#define BM 128
#define BN 128
#define BK 64
#define TPB 16     // M-tiles per block (persistent strip)

typedef __attribute__((ext_vector_type(4))) float f32x4;
typedef __attribute__((ext_vector_type(8))) short bf16x8;

__device__ inline short f2bf(float x) {
    union { __hip_bfloat16 b; short s; } u;
    u.b = __float2bfloat16(x);   // RNE
    return u.s;
}

__device__ inline void gload_lds16(const void* g, void* l) {
    __builtin_amdgcn_global_load_lds((const __attribute__((address_space(1))) void*)g,
                                     (__attribute__((address_space(3))) void*)l,
                                     16, 0, 0);
}

// ---------------- prep: bf16 conversion + reciprocal norms ----------------
__global__ __launch_bounds__(256) void prep_k(const float* __restrict__ A,
                                              const float* __restrict__ Bm,
                                              short* __restrict__ Abf,
                                              short* __restrict__ Bbf,
                                              float* __restrict__ rt,
                                              float* __restrict__ rl) {
    int gw   = (blockIdx.x * 256 + threadIdx.x) >> 6;
    int lane = threadIdx.x & 63;
    if (gw >= NT + NL) return;
    const float* src = (gw < NT) ? (A + (size_t)gw * DD) : (Bm + (size_t)(gw - NT) * DD);
    short*       dst = (gw < NT) ? (Abf + (size_t)gw * DD) : (Bbf + (size_t)(gw - NT) * DD);
    float4 v = reinterpret_cast<const float4*>(src)[lane];
    short4 o;
    o.x = f2bf(v.x); o.y = f2bf(v.y); o.z = f2bf(v.z); o.w = f2bf(v.w);
    reinterpret_cast<short4*>(dst)[lane] = o;
    float s = v.x * v.x + v.y * v.y + v.z * v.z + v.w * v.w;
#pragma unroll
    for (int off = 32; off > 0; off >>= 1) s += __shfl_xor(s, off);
    if (lane == 0) {
        float r = 1.0f / fmaxf(sqrtf(s), 1e-20f);
        if (gw < NT) rt[gw] = r; else rl[gw - NT] = r;
    }
}

// ---------------- persistent-strip bf16 GEMM, counted-vmcnt pipeline ------
// Identical to round-8 kernel EXCEPT: C stores are non-temporal (nt flag,
// no L2 allocate) so the 268 MB C stream stops evicting the A panels from
// each XCD's 4 MiB L2 (A working set/XCD = 4 strips x 1 MB = full L2).
__global__ __launch_bounds__(512, 2) void cosim_bf_k(const short* __restrict__ Abf,
                                                     const short* __restrict__ Bbf,
                                                     const float* __restrict__ rt,
                                                     const float* __restrict__ rl,
                                                     float* __restrict__ C) {
    __shared__ short Bs[BN * DD];        // 64 KB, full-K B tile
    __shared__ short As[4][BM * BK];     // 64 KB, 4-deep A ring
    __shared__ float rnA[TPB * BM];      // 8 KB
    __shared__ float rnB[BN];            // 0.5 KB

    const int tid  = threadIdx.x;
    const int lane = tid & 63;
    const int w    = tid >> 6;       // 0..7
    const int wr   = w >> 2;         // wave row 0..1 (64 rows)
    const int wc   = w & 3;          // wave col 0..3 (32 cols)

    const int xcd   = blockIdx.x & 7;
    const int g2    = blockIdx.x >> 3;   // 0..31
    const int bx    = g2 & 7;
    const int sub   = g2 >> 3;           // 0..3
    const int strip = xcd * 4 + sub;     // 0..31
    const int m0b   = strip * (TPB * BM);
    const int l0    = bx * BN;

    // ---- stage B (full K), source-chunk XOR swizzle ----
    {
        const int r2 = lane >> 5;        // row within pair
        const int ch = lane & 31;        // 16B chunk 0..31
#pragma unroll
        for (int i = 0; i < 8; ++i) {
            int rbase = w * 16 + i * 2;
            int row   = rbase + r2;
            int cg    = ch ^ (row & 7);
            gload_lds16(Bbf + (size_t)(l0 + row) * DD + cg * 8, &Bs[rbase * DD]);
        }
    }
    // ---- preload reciprocal norms into LDS ----
#pragma unroll
    for (int i = 0; i < 4; ++i) {
        int r = tid + i * 512;
        rnA[r] = rt[m0b + r];
    }
    if (tid < BN) rnB[tid] = rl[l0 + tid];
    __syncthreads();                     // drains B-stage vmcnt + norm lgkm

    // ---- A staging: stage g = tile (g>>2), k-slice (g&3), ring buf g&3 ----
    const int r8  = lane >> 3;
    const int ch8 = lane & 7;
    const int cg8 = ch8 ^ r8;
    auto stageA = [&](int g) {
        const short* base = Abf + (size_t)(m0b + (g >> 2) * BM) * DD + (g & 3) * BK;
        short* dst = As[g & 3];
#pragma unroll
        for (int i = 0; i < 2; ++i) {
            int rbase = w * 16 + i * 8;
            gload_lds16(base + (size_t)(rbase + r8) * DD + cg8 * 8, &dst[rbase * BK]);
        }
    };

    stageA(0);
    stageA(1);

    const int fr = lane & 15;
    const int fq = lane >> 4;
    const int cc = lane & 15;

#pragma unroll 1
    for (int t = 0; t < TPB; ++t) {
        f32x4 acc[4][2] = {};
#pragma unroll
        for (int kt = 0; kt < 4; ++kt) {
            const int g = t * 4 + kt;
            if (kt == 0) {
                stageA(g + 2);
                if (t == 0) asm volatile("s_waitcnt vmcnt(4)" ::: "memory");
                else        asm volatile("s_waitcnt vmcnt(36)" ::: "memory");
            } else if (kt == 1) {
                stageA(g + 2);
                if (t == 0) asm volatile("s_waitcnt vmcnt(4)" ::: "memory");
                else        asm volatile("s_waitcnt vmcnt(34)" ::: "memory");
            } else if (kt == 2) {
                if (t < TPB - 1) { stageA(g + 2); asm volatile("s_waitcnt vmcnt(4)" ::: "memory"); }
                else             { asm volatile("s_waitcnt vmcnt(2)" ::: "memory"); }
            } else {
                if (t < TPB - 1) { stageA(g + 2); asm volatile("s_waitcnt vmcnt(4)" ::: "memory"); }
                else             { asm volatile("s_waitcnt vmcnt(0)" ::: "memory"); }
            }
            __builtin_amdgcn_s_barrier();   // all waves' stage(g) landed

            const short* A_ = As[g & 3];
#pragma unroll
            for (int ks = 0; ks < 2; ++ks) {
                bf16x8 af[4], bf2[2];
#pragma unroll
                for (int i = 0; i < 4; ++i) {
                    int row = wr * 64 + i * 16 + fr;
                    int ck  = (ks * 4 + fq) ^ (row & 7);        // deswizzle
                    af[i] = *reinterpret_cast<const bf16x8*>(&A_[row * BK + ck * 8]);
                }
#pragma unroll
                for (int j = 0; j < 2; ++j) {
                    int row = wc * 32 + j * 16 + fr;
                    int c   = kt * 8 + ks * 4 + fq;              // full-K chunk
                    int ck  = c ^ (row & 7);
                    bf2[j] = *reinterpret_cast<const bf16x8*>(&Bs[row * DD + ck * 8]);
                }
#pragma unroll
                for (int i = 0; i < 4; ++i)
#pragma unroll
                    for (int j = 0; j < 2; ++j)
                        acc[i][j] = __builtin_amdgcn_mfma_f32_16x16x32_bf16(
                            af[i], bf2[j], acc[i][j], 0, 0, 0);
            }
        }

        // epilogue tile t — NON-TEMPORAL stores (no L2 allocate)
        const int m0 = m0b + t * BM;
#pragma unroll
        for (int i = 0; i < 4; ++i) {
#pragma unroll
            for (int rr = 0; rr < 4; ++rr) {
                int lr = wr * 64 + i * 16 + fq * 4 + rr;
                float rs = rnA[t * BM + lr];
                float* crow = C + (size_t)(m0 + lr) * NL + l0;
#pragma unroll
                for (int j = 0; j < 2; ++j) {
                    int lc = wc * 32 + j * 16 + cc;
                    __builtin_nontemporal_store(acc[i][j][rr] * rs * rnB[lc], &crow[lc]);
                }
            }
        }
    }
}

// ---------------- fallback (round-1 fused path, ws too small) -------------
__global__ __launch_bounds__(256) void norms_k(const float* __restrict__ A,
                                               const float* __restrict__ Bm,
                                               float* __restrict__ rt,
                                               float* __restrict__ rl) {
    int gw   = (blockIdx.x * 256 + threadIdx.x) >> 6;
    int lane = threadIdx.x & 63;
    if (gw >= NT + NL) return;
    const float* src = (gw < NT) ? (A + (size_t)gw * DD) : (Bm + (size_t)(gw - NT) * DD);
    float4 v = reinterpret_cast<const float4*>(src)[lane];
    float s = v.x * v.x + v.y * v.y + v.z * v.z + v.w * v.w;
#pragma unroll
    for (int off = 32; off > 0; off >>= 1) s += __shfl_xor(s, off);
    if (lane == 0) {
        float r = 1.0f / fmaxf(sqrtf(s), 1e-20f);
        if (gw < NT) rt[gw] = r; else rl[gw - NT] = r;
    }
}

__global__ __launch_bounds__(256, 2) void cosim_fused_k(const float* __restrict__ A,
                                                        const float* __restrict__ Bm,
                                                        const float* __restrict__ rt,
                                                        const float* __restrict__ rl,
                                                        float* __restrict__ C) {
    __shared__ short As[BM * BK];
    __shared__ short Bs[BN * BK];
    const int tid  = threadIdx.x;
    const int lane = tid & 63;
    const int wid  = tid >> 6;
    const int wr   = wid >> 1;
    const int wc   = wid & 1;
    const int orig = blockIdx.x;
    const int id   = (orig & 7) * (4096 / 8) + (orig >> 3);
    const int bx   = id & 7;
    const int by   = id >> 3;
    const int m0 = by * BM;
    const int l0 = bx * BN;
    const int srow = tid >> 4;
    const int sc4  = tid & 15;
    f32x4 ra[8], rb[8];
    auto loadg = [&](int kt) {
        const float* pa = A  + (size_t)m0 * DD + kt * BK;
        const float* pb = Bm + (size_t)l0 * DD + kt * BK;
#pragma unroll
        for (int i = 0; i < 8; ++i) {
            int row = srow + i * 16;
            ra[i] = reinterpret_cast<const f32x4*>(pa + (size_t)row * DD)[sc4];
            rb[i] = reinterpret_cast<const f32x4*>(pb + (size_t)row * DD)[sc4];
        }
    };
    auto stash = [&]() {
#pragma unroll
        for (int i = 0; i < 8; ++i) {
            int row = srow + i * 16;
            short4 pa, pb;
            pa.x = f2bf(ra[i].x); pa.y = f2bf(ra[i].y);
            pa.z = f2bf(ra[i].z); pa.w = f2bf(ra[i].w);
            pb.x = f2bf(rb[i].x); pb.y = f2bf(rb[i].y);
            pb.z = f2bf(rb[i].z); pb.w = f2bf(rb[i].w);
            *reinterpret_cast<short4*>(&As[row * BK + sc4 * 4]) = pa;
            *reinterpret_cast<short4*>(&Bs[row * BK + sc4 * 4]) = pb;
        }
    };
    f32x4 acc[4][4] = {};
    loadg(0);
#pragma unroll
    for (int kt = 0; kt < DD / BK; ++kt) {
        __syncthreads();
        stash();
        __syncthreads();
        if (kt < DD / BK - 1) loadg(kt + 1);
#pragma unroll
        for (int ks = 0; ks < 2; ++ks) {
            bf16x8 af[4], bfr[4];
            const int kof = ks * 32 + (lane >> 4) * 8;
            const int ar  = wr * 64 + (lane & 15);
            const int bc  = wc * 64 + (lane & 15);
#pragma unroll
            for (int i = 0; i < 4; ++i)
                af[i] = *reinterpret_cast<const bf16x8*>(&As[(ar + i * 16) * BK + kof]);
#pragma unroll
            for (int j = 0; j < 4; ++j)
                bfr[j] = *reinterpret_cast<const bf16x8*>(&Bs[(bc + j * 16) * BK + kof]);
#pragma unroll
            for (int i = 0; i < 4; ++i)
#pragma unroll
                for (int j = 0; j < 4; ++j)
                    acc[i][j] = __builtin_amdgcn_mfma_f32_16x16x32_bf16(
                        af[i], bfr[j], acc[i][j], 0, 0, 0);
        }
    }
    const int crow0 = m0 + wr * 64;
    const int ccol0 = l0 + wc * 64;
    const int rq = lane >> 4;
    const int cc = lane & 15;
#pragma unroll
    for (int i = 0; i < 4; ++i) {
#pragma unroll
        for (int r = 0; r < 4; ++r) {
            int row = crow0 + i * 16 + rq * 4 + r;
            float rsc = rt[row];
            float* crow = C + (size_t)row * NL;
#pragma unroll
            for (int j = 0; j < 4; ++j) {
                int col = ccol0 + j * 16 + cc;
                crow[col] = acc[i][j][r] * rsc * rl[col];
            }
        }
    }
}

extern "C" void kernel_launch(void* const* d_in, const int* in_sizes, int n_in,
                              void* d_out, int out_size, void* d_ws, size_t ws_size,
                              hipStream_t stream) {
    const float* A  = (const float*)d_in[0];   // [65536,256] fp32
    const float* Bm = (const float*)d_in[1];   // [1024,256]  fp32
    float* C = (float*)d_out;                  // [65536,1024] fp32

    const size_t abf_elems = (size_t)NT * DD;
    const size_t bbf_elems = (size_t)NL * DD;
    const size_t need = (abf_elems + bbf_elems) * sizeof(short)
                      + (NT + NL) * sizeof(float);

    if (ws_size >= need) {
        short* Abf = (short*)d_ws;
        short* Bbf = Abf + abf_elems;
        float* rt  = (float*)(Bbf + bbf_elems);
        float* rl  = rt + NT;
        prep_k<<<(NT + NL) / 4, 256, 0, stream>>>(A, Bm, Abf, Bbf, rt, rl);
        cosim_bf_k<<<256, 512, 0, stream>>>(Abf, Bbf, rt, rl, C);
    } else {
        float* rt = (float*)d_ws;
        float* rl = rt + NT;
        norms_k<<<(NT + NL) / 4, 256, 0, stream>>>(A, Bm, rt, rl);
        cosim_fused_k<<<(NL / BN) * (NT / BM), 256, 0, stream>>>(A, Bm, rt, rl, C);
    }
}